// Round 3
// baseline (298.682 us; speedup 1.0000x reference)
//
#include <hip/hip_runtime.h>

#define NNODES 65536
#define CC 128
#define NEL 10
#define BN 32
#define NT 256

#define INV_SQ2f 0.70710678118654752440f
#define INV_SQ6f 0.40824829046386301637f
#define INV_2Cf  0.0625f               /* 1/sqrt(256) */
#define INV_Cf   0.08838834764831845f  /* 1/sqrt(128) */
#define S16f 0.25f
#define S64f 0.125f

#define WS_FRAGS 312
#define WS_BYTES (WS_FRAGS * 1024)
#define XBUF 4352   /* 32 rows * 136 ushorts */

typedef __attribute__((ext_vector_type(8))) short s16x8;
typedef __attribute__((ext_vector_type(4))) float f32x4;
#define MFMA16(a, b, c) __builtin_amdgcn_mfma_f32_16x16x32_bf16((a), (b), (c), 0, 0, 0)

union U8 { unsigned short u[8]; s16x8 s; };

__device__ __forceinline__ unsigned short bf16rne(float x) {
    unsigned int u = __float_as_uint(x);
    return (unsigned short)((u + 0x7FFFu + ((u >> 16) & 1u)) >> 16);
}
__device__ __forceinline__ float bf2f(unsigned short h) {
    return __uint_as_float(((unsigned int)h) << 16);
}
__device__ __forceinline__ unsigned int packbf(float a, float b) {
    return (unsigned int)bf16rne(a) | (((unsigned int)bf16rne(b)) << 16);
}
__device__ __forceinline__ float siluf(float x) {
    return x * (1.0f / (1.0f + __expf(-x)));
}

// ---------------- weight fragment prep (one-shot, 312 frags) ----------------
// frag f of matrix (K x N): lane l holds 8 bf16 along K:
//   col n = nt*16 + (l&15), k = ks*32 + (l>>4)*8 + j  (zero if k>=K)
extern "C" __global__ void prep_frags(
    const float* __restrict__ WC1, const float* __restrict__ WC2,
    const float* __restrict__ WC3, const float* __restrict__ WB1,
    const float* __restrict__ WB2, const float* __restrict__ WB3,
    const float* __restrict__ WC4, const float* __restrict__ WB4,
    const float* __restrict__ WL0, const float* __restrict__ WO0,
    const float* __restrict__ WL1, const float* __restrict__ WO1,
    unsigned short* __restrict__ wsb)
{
    const int b = blockIdx.x;
    const int l = threadIdx.x;
    const float* W; int K, N, nKS, base; float sc;
    if      (b <  4) { W = WC1; K = 16;  N = 64;  nKS = 1; base = 0;   sc = S16f; }
    else if (b < 12) { W = WC2; K = 64;  N = 64;  nKS = 2; base = 4;   sc = S64f; }
    else if (b < 20) { W = WC3; K = 64;  N = 64;  nKS = 2; base = 12;  sc = S64f; }
    else if (b < 24) { W = WB1; K = 16;  N = 64;  nKS = 1; base = 20;  sc = S16f; }
    else if (b < 32) { W = WB2; K = 64;  N = 64;  nKS = 2; base = 24;  sc = S64f; }
    else if (b < 40) { W = WB3; K = 64;  N = 64;  nKS = 2; base = 32;  sc = S64f; }
    else if (b < 104){ W = WC4; K = 64;  N = 512; nKS = 2; base = 40;  sc = S64f; }
    else if (b < 120){ W = WB4; K = 64;  N = 128; nKS = 2; base = 104; sc = S64f; }
    else if (b < 184){ W = WL0; K = 256; N = 128; nKS = 8; base = 120; sc = INV_2Cf; }
    else if (b < 216){ W = WO0; K = 128; N = 128; nKS = 4; base = 184; sc = INV_Cf; }
    else if (b < 280){ W = WL1; K = 256; N = 128; nKS = 8; base = 216; sc = INV_2Cf; }
    else             { W = WO1; K = 128; N = 128; nKS = 4; base = 280; sc = INV_Cf; }
    const int f  = b - base;
    const int nt = f / nKS, ks = f % nKS;
    const int n  = nt * 16 + (l & 15);
    const int k0 = ks * 32 + (l >> 4) * 8;
    U8 v;
    #pragma unroll
    for (int j = 0; j < 8; ++j) {
        const int k = k0 + j;
        const float x = (k < K) ? W[(size_t)k * N + n] * sc : 0.0f;
        v.u[j] = bf16rne(x);
    }
    *(s16x8*)(wsb + (size_t)b * 512 + l * 8) = v.s;
}

// ---------------- helpers ----------------
__device__ __forceinline__ s16x8 ldB(const unsigned short* __restrict__ wsb, int fragidx, int lane) {
    return *(const s16x8*)(wsb + ((size_t)fragidx << 9) + lane * 8);
}
__device__ __forceinline__ s16x8 ldA136(const unsigned short* X, int row, int ks, int gq) {
    return *(const s16x8*)(X + row * 136 + ks * 32 + gq * 8);
}

// w-chunk GEMM: wc[tc] = h3c-rows x WC4-chunk columns (K=64)
__device__ __forceinline__ void wchunk4(const unsigned short* __restrict__ wsb, int lane,
                                        int wbase, int ch, s16x8 h0, s16x8 h1, f32x4 wc[4]) {
    const f32x4 Z4 = {0.f, 0.f, 0.f, 0.f};
    #pragma unroll
    for (int tc = 0; tc < 4; ++tc) {
        const int nb = wbase + (ch * 4 + tc) * 2;
        f32x4 c = MFMA16(h0, ldB(wsb, nb, lane), Z4);
        wc[tc]  = MFMA16(h1, ldB(wsb, nb + 1, lane), c);
    }
}

// MLP hidden layer (64x64, K=64) with silu, H stride = 72 ushorts
__device__ __forceinline__ void mlp_layer(const unsigned short* __restrict__ wsb, int lane,
                                          int ng, int chm, int cl, int gq,
                                          const unsigned short* srcH, int bbase,
                                          unsigned short* dstH) {
    const f32x4 Z4 = {0.f, 0.f, 0.f, 0.f};
    const int rowA = ng * 16 + cl;
    f32x4 c0 = Z4, c1 = Z4;
    #pragma unroll
    for (int ks = 0; ks < 2; ++ks) {
        s16x8 a = *(const s16x8*)(srcH + rowA * 72 + ks * 32 + gq * 8);
        c0 = MFMA16(a, ldB(wsb, bbase + (chm * 2 + 0) * 2 + ks, lane), c0);
        c1 = MFMA16(a, ldB(wsb, bbase + (chm * 2 + 1) * 2 + ks, lane), c1);
    }
    #pragma unroll
    for (int r = 0; r < 4; ++r) {
        const int rw = ng * 16 + gq * 4 + r;
        dstH[rw * 72 + (chm * 2 + 0) * 16 + cl] = bf16rne(siluf(c0[r]));
        dstH[rw * 72 + (chm * 2 + 1) * 16 + cl] = bf16rne(siluf(c1[r]));
    }
}

// prefetch v component i for this thread's 16 channels (thread-linear layout)
__device__ __forceinline__ void pref_v(const float* __restrict__ Vin, int n0, int i, int tid, float* vr) {
    const int row = tid >> 3, c0 = (tid & 7) << 4;
    const size_t gn = (size_t)(n0 + row);
    #pragma unroll
    for (int j = 0; j < 16; ++j)
        vr[j] = Vin[((gn * CC) + c0 + j) * 3 + i];
}

// stage bv = b*v_i -> d1, gv = gate*v_i -> d3 (thread-linear dword pass)
__device__ __forceinline__ void stage_bvgv(const unsigned short* __restrict__ Xb,
                                           const unsigned short* __restrict__ Xgt,
                                           unsigned short* __restrict__ d1,
                                           unsigned short* __restrict__ d3,
                                           const float* vr, int tid) {
    const int dbase = (tid >> 3) * 68 + (tid & 7) * 8;
    const unsigned int* Xbd = (const unsigned int*)Xb;
    const unsigned int* Xgd = (const unsigned int*)Xgt;
    unsigned int* o1 = (unsigned int*)d1;
    unsigned int* o3 = (unsigned int*)d3;
    #pragma unroll
    for (int jp = 0; jp < 8; ++jp) {
        const unsigned int bd = Xbd[dbase + jp];
        const unsigned int gd = Xgd[dbase + jp];
        const float v0 = vr[2 * jp], v1 = vr[2 * jp + 1];
        o1[dbase + jp] = packbf(bf2f((unsigned short)(bd & 0xffff)) * v0,
                                bf2f((unsigned short)(bd >> 16)) * v1);
        o3[dbase + jp] = packbf(bf2f((unsigned short)(gd & 0xffff)) * v0,
                                bf2f((unsigned short)(gd >> 16)) * v1);
    }
}

// ---------------- main fused MFMA kernel ----------------
extern "C" __global__ void __launch_bounds__(NT, 4)
epb_mfma(const float* __restrict__ Sin, const float* __restrict__ Vin,
         const float* __restrict__ SCp, const float* __restrict__ ATT,
         const float* __restrict__ INVF, const float* __restrict__ MNA,
         const float* __restrict__ MLEN, const float* __restrict__ WSp,
         const float* __restrict__ WVp, const float* __restrict__ ESC,
         const unsigned short* __restrict__ wsb, float* __restrict__ OUT)
{
    extern __shared__ char smem[];
    unsigned short* X1 = (unsigned short*)smem;   // Hc ping / m0 / bv
    unsigned short* X2 = X1 + XBUF;               // Hb ping / m1 / b
    unsigned short* X3 = X2 + XBUF;               // Hc pong / out_s / a2 / gv
    unsigned short* Xg = X3 + XBUF;               // Hb pong / gate
    float* y0f  = (float*)(smem + 4 * XBUF * 2);  // [32]
    float* y1f  = y0f + 32;                       // [32][3]
    float* etf  = y1f + 96;                       // [32]
    int*   eidx = (int*)(etf + 32);               // [32]

    const int tid  = threadIdx.x;
    const int n0   = blockIdx.x * BN;
    const int wid  = tid >> 6;
    const int lane = tid & 63;
    const int ng   = wid >> 1;       // node group (16 rows)
    const int ch   = wid & 1;        // col half
    const int cl   = lane & 15;
    const int gq   = lane >> 4;
    const int rowA = ng * 16 + cl;
    const f32x4 Z4 = {0.f, 0.f, 0.f, 0.f};

    // ---- invl A-fragment (K=16 padded to 32) straight from global ----
    U8 invu;
    if (gq < 2) {
        const float* ip = INVF + (size_t)(n0 + rowA) * 16 + gq * 8;
        #pragma unroll
        for (int j = 0; j < 8; ++j) invu.u[j] = bf16rne(ip[j]);
    } else {
        #pragma unroll
        for (int j = 0; j < 8; ++j) invu.u[j] = 0;
    }
    const s16x8 invf = invu.s;

    // ---- P0: per-node smalls ----
    if (tid < BN) {
        const int gn = n0 + tid;
        y0f[tid] = MNA[gn * 4 + 0];
        y1f[tid * 3 + 0] = MNA[gn * 4 + 1];
        y1f[tid * 3 + 1] = MNA[gn * 4 + 2];
        y1f[tid * 3 + 2] = MNA[gn * 4 + 3];
        etf[tid] = 1.0f - __expf(-ESC[0] * MLEN[gn]);
        int e = 0;
        #pragma unroll
        for (int k = 0; k < NEL; ++k)
            if (ATT[(size_t)gn * NEL + k] > 0.5f) e = k;
        eidx[tid] = e;
    }

    // ---- L1 (both chains): invf @ WC1 -> X1, invf @ WB1 -> X2 ----
    {
        f32x4 c0 = MFMA16(invf, ldB(wsb, 0 + ch * 2 + 0, lane), Z4);
        f32x4 c1 = MFMA16(invf, ldB(wsb, 0 + ch * 2 + 1, lane), Z4);
        f32x4 b0 = MFMA16(invf, ldB(wsb, 20 + ch * 2 + 0, lane), Z4);
        f32x4 b1 = MFMA16(invf, ldB(wsb, 20 + ch * 2 + 1, lane), Z4);
        #pragma unroll
        for (int r = 0; r < 4; ++r) {
            const int rw = ng * 16 + gq * 4 + r;
            X1[rw * 72 + (ch * 2 + 0) * 16 + cl] = bf16rne(siluf(c0[r]));
            X1[rw * 72 + (ch * 2 + 1) * 16 + cl] = bf16rne(siluf(c1[r]));
            X2[rw * 72 + (ch * 2 + 0) * 16 + cl] = bf16rne(siluf(b0[r]));
            X2[rw * 72 + (ch * 2 + 1) * 16 + cl] = bf16rne(siluf(b1[r]));
        }
    }
    __syncthreads();   // B1
    // ---- L2 (both chains): X1 -> X3 (WC2), X2 -> Xg (WB2) ----
    mlp_layer(wsb, lane, ng, ch, cl, gq, X1, 4,  X3);
    mlp_layer(wsb, lane, ng, ch, cl, gq, X2, 24, Xg);
    __syncthreads();   // B2
    // ---- L3 (both chains): X3 -> X1 (WC3), Xg -> X2 (WB3) ----
    mlp_layer(wsb, lane, ng, ch, cl, gq, X3, 12, X1);
    mlp_layer(wsb, lane, ng, ch, cl, gq, Xg, 32, X2);
    __syncthreads();   // B3

    // ---- phase 5: h3 -> regs; ob MFMAs; P2 (out_s -> X3, gate -> Xg) ----
    const s16x8 h3c0 = *(const s16x8*)(X1 + rowA * 72 + 0 * 32 + gq * 8);
    const s16x8 h3c1 = *(const s16x8*)(X1 + rowA * 72 + 1 * 32 + gq * 8);
    const s16x8 h3b0 = *(const s16x8*)(X2 + rowA * 72 + 0 * 32 + gq * 8);
    const s16x8 h3b1 = *(const s16x8*)(X2 + rowA * 72 + 1 * 32 + gq * 8);

    f32x4 obacc[4];
    #pragma unroll
    for (int tc = 0; tc < 4; ++tc) {
        const int nb = 104 + (ch * 4 + tc) * 2;
        f32x4 c = MFMA16(h3b0, ldB(wsb, nb, lane), Z4);
        obacc[tc] = MFMA16(h3b1, ldB(wsb, nb + 1, lane), c);
    }

    {   // P2: thread-linear, 16 channels of one row per thread
        const int row = tid >> 3;
        const int c0  = (tid & 7) << 4;
        const size_t gn = (size_t)(n0 + row);
        const int e = eidx[row];
        const float* sp  = Sin + gn * CC + c0;
        const float* vp  = Vin + (gn * CC + c0) * 3;
        const float* wsp = WSp + ((size_t)e * 5) * CC + c0;
        const float* wvp = WVp + ((size_t)e * 4) * CC + c0;
        unsigned int* X3d = (unsigned int*)X3;
        unsigned int* Xgd = (unsigned int*)Xg;
        const int dbase = row * 68 + (c0 >> 1);
        #pragma unroll
        for (int jp = 0; jp < 8; ++jp) {
            const int c = 2 * jp;
            const float2 s2 = *(const float2*)(sp + c);
            const float2 va = *(const float2*)(vp + 3 * c);
            const float2 vb = *(const float2*)(vp + 3 * c + 2);
            const float2 vc = *(const float2*)(vp + 3 * c + 4);
            const float vv0 = va.x * va.x + va.y * va.y + vb.x * vb.x;
            const float vv1 = vb.y * vb.y + vc.x * vc.x + vc.y * vc.y;
            const float2 p0 = *(const float2*)(wsp + 0 * CC + c);
            const float2 p1 = *(const float2*)(wsp + 1 * CC + c);
            const float2 p2 = *(const float2*)(wsp + 2 * CC + c);
            const float2 p3 = *(const float2*)(wsp + 3 * CC + c);
            const float2 p4 = *(const float2*)(wsp + 4 * CC + c);
            const float2 q0 = *(const float2*)(wvp + 0 * CC + c);
            const float2 q1 = *(const float2*)(wvp + 1 * CC + c);
            const float2 q2 = *(const float2*)(wvp + 2 * CC + c);
            const float2 q3 = *(const float2*)(wvp + 3 * CC + c);
            const float s0 = s2.x, s1 = s2.y;
            const float ss0 = s0 * s0, ss1 = s1 * s1;
            const float os0 = p0.x * s0 + p1.x * ss0 + p2.x * vv0 + p3.x * (ss0 * s0) + p4.x * (s0 * vv0);
            const float os1 = p0.y * s1 + p1.y * ss1 + p2.y * vv1 + p3.y * (ss1 * s1) + p4.y * (s1 * vv1);
            const float gt0 = q0.x + q1.x * s0 + q2.x * ss0 + q3.x * vv0;
            const float gt1 = q0.y + q1.y * s1 + q2.y * ss1 + q3.y * vv1;
            X3d[dbase + jp] = packbf(os0, os1);
            Xgd[dbase + jp] = packbf(gt0, gt1);
        }
    }
    __syncthreads();   // B4

    // ---- phase 6: m1 -> X2, m0 -> X1 (single phase) ----
    {
        f32x4 wc1[4], wc0[4];
        wchunk4(wsb, lane, 40 + 8 * 2, ch, h3c0, h3c1, wc1);   // w1 chunk
        wchunk4(wsb, lane, 40,         ch, h3c0, h3c1, wc0);   // w0 chunk
        #pragma unroll
        for (int tc = 0; tc < 4; ++tc) {
            #pragma unroll
            for (int r = 0; r < 4; ++r) {
                const int rw = ng * 16 + gq * 4 + r;
                const int col = ch * 64 + tc * 16 + cl;
                const float gt = bf2f(Xg[rw * 136 + col]);
                const float* vp = Vin + ((size_t)(n0 + rw) * CC + col) * 3;
                const float vy = vp[0] * y1f[rw * 3] + vp[1] * y1f[rw * 3 + 1] + vp[2] * y1f[rw * 3 + 2];
                X2[rw * 136 + col] = bf16rne(INV_SQ6f * wc1[tc][r] * gt * vy);
                const float os = bf2f(X3[rw * 136 + col]);
                const float m0 = INV_SQ2f * wc0[tc][r] * os * y0f[rw] + etf[rw] * obacc[tc][r];
                X1[rw * 136 + col] = bf16rne(m0);
            }
        }
    }
    __syncthreads();   // B5

    // ---- G1: msg0 = [m0|m1|os] @ [Wl0a;Wl0b;Wo0] + sc ----
    {
        f32x4 acc[4] = {Z4, Z4, Z4, Z4};
        #pragma unroll
        for (int ks = 0; ks < 12; ++ks) {
            const unsigned short* Xa = (ks < 4) ? X1 : (ks < 8) ? X2 : X3;
            const s16x8 a = ldA136(Xa, rowA, ks & 3, gq);
            #pragma unroll
            for (int tc = 0; tc < 4; ++tc) {
                const int fi = (ks < 8) ? (120 + (ch * 4 + tc) * 8 + ks)
                                        : (184 + (ch * 4 + tc) * 4 + (ks - 8));
                acc[tc] = MFMA16(a, ldB(wsb, fi, lane), acc[tc]);
            }
        }
        #pragma unroll
        for (int tc = 0; tc < 4; ++tc) {
            #pragma unroll
            for (int r = 0; r < 4; ++r) {
                const int rw = ng * 16 + gq * 4 + r;
                const size_t o = (size_t)(n0 + rw) * 512 + ch * 64 + tc * 16 + cl;
                OUT[o] = acc[tc][r] + SCp[o];
            }
        }
    }
    __syncthreads();   // B6

    // ---- phase 8: a2 = INV_SQ2*w2*out_s (X3 in place); b = INV_SQ2*w3*gate*y0 -> X2 ----
    float vr[16];
    pref_v(Vin, n0, 0, tid, vr);   // overlap v0 loads with this phase
    {
        f32x4 wc2[4], wc3[4];
        wchunk4(wsb, lane, 40 + 16 * 2, ch, h3c0, h3c1, wc2);
        wchunk4(wsb, lane, 40 + 24 * 2, ch, h3c0, h3c1, wc3);
        #pragma unroll
        for (int tc = 0; tc < 4; ++tc) {
            #pragma unroll
            for (int r = 0; r < 4; ++r) {
                const int rw = ng * 16 + gq * 4 + r;
                const int col = ch * 64 + tc * 16 + cl;
                X3[rw * 136 + col] = bf16rne(INV_SQ2f * wc2[tc][r] * bf2f(X3[rw * 136 + col]));
                const float gt = bf2f(Xg[rw * 136 + col]);
                X2[rw * 136 + col] = bf16rne(INV_SQ2f * wc3[tc][r] * gt * y0f[rw]);
            }
        }
    }
    __syncthreads();   // B7

    // ---- G2: t = a2 @ Wl1[0:128] -> tacc ----
    f32x4 tacc[4] = {Z4, Z4, Z4, Z4};
    #pragma unroll
    for (int ks = 0; ks < 4; ++ks) {
        const s16x8 a = ldA136(X3, rowA, ks, gq);
        #pragma unroll
        for (int tc = 0; tc < 4; ++tc)
            tacc[tc] = MFMA16(a, ldB(wsb, 216 + (ch * 4 + tc) * 8 + ks, lane), tacc[tc]);
    }
    __syncthreads();   // B8

    // ---- G3: 3 components, staged ping through X1 (bv) / X3 (gv) ----
    f32x4 acc3[3][4];
    stage_bvgv(X2, Xg, X1, X3, vr, tid);
    __syncthreads();   // B9
    #pragma unroll
    for (int i = 0; i < 3; ++i) {
        if (i < 2) pref_v(Vin, n0, i + 1, tid, vr);   // overlap next v loads with MFMAs
        #pragma unroll
        for (int tc = 0; tc < 4; ++tc) acc3[i][tc] = Z4;
        #pragma unroll
        for (int ks = 0; ks < 4; ++ks) {
            const s16x8 a1 = ldA136(X1, rowA, ks, gq);
            const s16x8 a3 = ldA136(X3, rowA, ks, gq);
            #pragma unroll
            for (int tc = 0; tc < 4; ++tc) {
                acc3[i][tc] = MFMA16(a1, ldB(wsb, 216 + (ch * 4 + tc) * 8 + 4 + ks, lane), acc3[i][tc]);
                acc3[i][tc] = MFMA16(a3, ldB(wsb, 280 + (ch * 4 + tc) * 4 + ks, lane), acc3[i][tc]);
            }
        }
        if (i < 2) {
            __syncthreads();   // GEMM i done reading
            stage_bvgv(X2, Xg, X1, X3, vr, tid);
            __syncthreads();   // stage i+1 visible
        }
    }

    // ---- epilogue: msg1 = G3 + t*y1_i + sc, contiguous stores ----
    #pragma unroll
    for (int tc = 0; tc < 4; ++tc) {
        #pragma unroll
        for (int r = 0; r < 4; ++r) {
            const int rw = ng * 16 + gq * 4 + r;
            const int col = ch * 64 + tc * 16 + cl;
            const size_t base = (size_t)(n0 + rw) * 512 + 128 + (size_t)col * 3;
            const float tv = tacc[tc][r];
            #pragma unroll
            for (int i = 0; i < 3; ++i) {
                const size_t o = base + i;
                OUT[o] = acc3[i][tc][r] + tv * y1f[rw * 3 + i] + SCp[o];
            }
        }
    }
}

extern "C" void kernel_launch(void* const* d_in, const int* in_sizes, int n_in,
                              void* d_out, int out_size, void* d_ws, size_t ws_size,
                              hipStream_t stream)
{
    (void)in_sizes; (void)n_in; (void)out_size; (void)ws_size;
    const float* Sin  = (const float*)d_in[0];
    const float* Vin  = (const float*)d_in[1];
    const float* SCp  = (const float*)d_in[2];
    const float* ATT  = (const float*)d_in[3];
    const float* INVF = (const float*)d_in[4];
    const float* MNA  = (const float*)d_in[5];
    const float* MLEN = (const float*)d_in[6];
    const float* WSp  = (const float*)d_in[7];
    const float* WVp  = (const float*)d_in[8];
    const float* WC1  = (const float*)d_in[9];
    const float* WC2  = (const float*)d_in[10];
    const float* WC3  = (const float*)d_in[11];
    const float* WC4  = (const float*)d_in[12];
    const float* WB1  = (const float*)d_in[13];
    const float* WB2  = (const float*)d_in[14];
    const float* WB3  = (const float*)d_in[15];
    const float* WB4  = (const float*)d_in[16];
    const float* ESC  = (const float*)d_in[17];
    const float* WL0  = (const float*)d_in[18];
    const float* WL1  = (const float*)d_in[19];
    const float* WO0  = (const float*)d_in[20];
    const float* WO1  = (const float*)d_in[21];
    float* OUT = (float*)d_out;

    unsigned short* wsb = (unsigned short*)d_ws;
    hipLaunchKernelGGL(prep_frags, dim3(WS_FRAGS), dim3(64), 0, stream,
                       WC1, WC2, WC3, WB1, WB2, WB3, WC4, WB4,
                       WL0, WO0, WL1, WO1, wsb);
    // dynamic LDS: 4 X-buffers (8704 B each) + smalls = 35584 B -> 4 blocks/CU
    const size_t shbytes = (size_t)(4 * XBUF * 2 + (32 + 96 + 32 + 32) * 4);
    hipLaunchKernelGGL(epb_mfma, dim3(NNODES / BN), dim3(NT), shbytes, stream,
                       Sin, Vin, SCp, ATT, INVF, MNA, MLEN, WSp, WVp, ESC,
                       wsb, OUT);
}

// Round 4
// 239.277 us; speedup vs baseline: 1.2483x; 1.2483x over previous
//
#include <hip/hip_runtime.h>

#define NNODES 65536
#define CC 128
#define NEL 10
#define BN 32
#define NT 256

#define INV_SQ2f 0.70710678118654752440f
#define INV_SQ6f 0.40824829046386301637f
#define INV_2Cf  0.0625f               /* 1/sqrt(256) */
#define INV_Cf   0.08838834764831845f  /* 1/sqrt(128) */
#define S16f 0.25f
#define S64f 0.125f

#define WS_FRAGS 312
#define WS_BYTES (WS_FRAGS * 1024)

typedef __attribute__((ext_vector_type(8))) short s16x8;
typedef __attribute__((ext_vector_type(4))) float f32x4;
#define MFMA16(a, b, c) __builtin_amdgcn_mfma_f32_16x16x32_bf16((a), (b), (c), 0, 0, 0)

union U8 { unsigned short u[8]; s16x8 s; };

__device__ __forceinline__ unsigned short bf16rne(float x) {
    unsigned int u = __float_as_uint(x);
    return (unsigned short)((u + 0x7FFFu + ((u >> 16) & 1u)) >> 16);
}
__device__ __forceinline__ float bf2f(unsigned short h) {
    return __uint_as_float(((unsigned int)h) << 16);
}
__device__ __forceinline__ unsigned int packbf(float a, float b) {
    return (unsigned int)bf16rne(a) | (((unsigned int)bf16rne(b)) << 16);
}
__device__ __forceinline__ float siluf(float x) {
    return x * (1.0f / (1.0f + __expf(-x)));
}

// ---------------- weight fragment prep (one-shot, 312 frags) ----------------
// frag f of matrix (K x N): lane l holds 8 bf16 along K:
//   col n = nt*16 + (l&15), k = ks*32 + (l>>4)*8 + j  (zero if k>=K)
extern "C" __global__ void prep_frags(
    const float* __restrict__ WC1, const float* __restrict__ WC2,
    const float* __restrict__ WC3, const float* __restrict__ WB1,
    const float* __restrict__ WB2, const float* __restrict__ WB3,
    const float* __restrict__ WC4, const float* __restrict__ WB4,
    const float* __restrict__ WL0, const float* __restrict__ WO0,
    const float* __restrict__ WL1, const float* __restrict__ WO1,
    unsigned short* __restrict__ wsb)
{
    const int b = blockIdx.x;
    const int l = threadIdx.x;
    const float* W; int K, N, nKS, base; float sc;
    if      (b <  4) { W = WC1; K = 16;  N = 64;  nKS = 1; base = 0;   sc = S16f; }
    else if (b < 12) { W = WC2; K = 64;  N = 64;  nKS = 2; base = 4;   sc = S64f; }
    else if (b < 20) { W = WC3; K = 64;  N = 64;  nKS = 2; base = 12;  sc = S64f; }
    else if (b < 24) { W = WB1; K = 16;  N = 64;  nKS = 1; base = 20;  sc = S16f; }
    else if (b < 32) { W = WB2; K = 64;  N = 64;  nKS = 2; base = 24;  sc = S64f; }
    else if (b < 40) { W = WB3; K = 64;  N = 64;  nKS = 2; base = 32;  sc = S64f; }
    else if (b < 104){ W = WC4; K = 64;  N = 512; nKS = 2; base = 40;  sc = S64f; }
    else if (b < 120){ W = WB4; K = 64;  N = 128; nKS = 2; base = 104; sc = S64f; }
    else if (b < 184){ W = WL0; K = 256; N = 128; nKS = 8; base = 120; sc = INV_2Cf; }
    else if (b < 216){ W = WO0; K = 128; N = 128; nKS = 4; base = 184; sc = INV_Cf; }
    else if (b < 280){ W = WL1; K = 256; N = 128; nKS = 8; base = 216; sc = INV_2Cf; }
    else             { W = WO1; K = 128; N = 128; nKS = 4; base = 280; sc = INV_Cf; }
    const int f  = b - base;
    const int nt = f / nKS, ks = f % nKS;
    const int n  = nt * 16 + (l & 15);
    const int k0 = ks * 32 + (l >> 4) * 8;
    U8 v;
    #pragma unroll
    for (int j = 0; j < 8; ++j) {
        const int k = k0 + j;
        const float x = (k < K) ? W[(size_t)k * N + n] * sc : 0.0f;
        v.u[j] = bf16rne(x);
    }
    *(s16x8*)(wsb + (size_t)b * 512 + l * 8) = v.s;
}

// ---------------- helpers ----------------
__device__ __forceinline__ s16x8 ldB(const unsigned short* __restrict__ wsb, int fragidx, int lane) {
    return *(const s16x8*)(wsb + ((size_t)fragidx << 9) + lane * 8);
}
__device__ __forceinline__ s16x8 ldA136(const unsigned short* X, int row, int ks, int gq) {
    return *(const s16x8*)(X + row * 136 + ks * 32 + gq * 8);
}
__device__ __forceinline__ s16x8 ldA72(const unsigned short* X, int row, int ks, int gq) {
    return *(const s16x8*)(X + row * 72 + ks * 32 + gq * 8);
}

// ---------------- main fused MFMA kernel ----------------
// NT=256, 4 waves. Wave w owns ALL 32 rows x its own column slice:
//   128-wide phases: col tiles T = w*2+tc (tc=0,1), col = T*16 + cl
//   64-wide MLP:     col tile w,              col = w*16 + cl
// => each weight fragment is read exactly once per block (B-frag traffic /2).
extern "C" __global__ void __launch_bounds__(NT, 4)
epb_mfma(const float* __restrict__ Sin, const float* __restrict__ Vin,
         const float* __restrict__ SCp, const float* __restrict__ ATT,
         const float* __restrict__ INVF, const float* __restrict__ MNA,
         const float* __restrict__ MLEN, const float* __restrict__ WSp,
         const float* __restrict__ WVp, const float* __restrict__ ESC,
         const unsigned short* __restrict__ wsb, float* __restrict__ OUT)
{
    extern __shared__ char smem[];
    // 4 buffers of [32][136] ushort (8704 B). MLP H-chain aliases (stride 72).
    unsigned short* B1 = (unsigned short*)smem;          // Hc1/Hc3 -> out_s -> a2 -> bv
    unsigned short* B2 = B1 + 4352;                      // Hb1/Hb3 -> gate (persists)
    unsigned short* B3 = B2 + 4352;                      // Hc2 -> vy -> m1 -> gv
    unsigned short* B4 = B3 + 4352;                      // Hb2 -> m0 -> b
    float* y0f  = (float*)(smem + 4 * 8704);             // [32]
    float* y1f  = y0f + 32;                              // [32][3]
    float* etf  = y1f + 96;                              // [32]
    int*   eidx = (int*)(etf + 32);                      // [32]

    const int tid  = threadIdx.x;
    const int n0   = blockIdx.x * BN;
    const int w    = tid >> 6;       // wave id: column-slice owner
    const int lane = tid & 63;
    const int cl   = lane & 15;
    const int gq   = lane >> 4;
    const f32x4 Z4 = {0.f, 0.f, 0.f, 0.f};

    // ---- inv A-fragments for both row-groups (K=16 padded to 32) ----
    U8 invu[2];
    #pragma unroll
    for (int rg = 0; rg < 2; ++rg) {
        if (gq < 2) {
            const float* ip = INVF + (size_t)(n0 + rg * 16 + cl) * 16 + gq * 8;
            #pragma unroll
            for (int j = 0; j < 8; ++j) invu[rg].u[j] = bf16rne(ip[j]);
        } else {
            #pragma unroll
            for (int j = 0; j < 8; ++j) invu[rg].u[j] = 0;
        }
    }

    // ---- P0: per-node smalls ----
    if (tid < BN) {
        const int gn = n0 + tid;
        y0f[tid] = MNA[gn * 4 + 0];
        y1f[tid * 3 + 0] = MNA[gn * 4 + 1];
        y1f[tid * 3 + 1] = MNA[gn * 4 + 2];
        y1f[tid * 3 + 2] = MNA[gn * 4 + 3];
        etf[tid] = 1.0f - __expf(-ESC[0] * MLEN[gn]);
        int e = 0;
        #pragma unroll
        for (int k = 0; k < NEL; ++k)
            if (ATT[(size_t)gn * NEL + k] > 0.5f) e = k;
        eidx[tid] = e;
    }

    // ---- L1 (both chains): inv @ WC1 -> B1, inv @ WB1 -> B2 ----
    {
        #pragma unroll
        for (int rg = 0; rg < 2; ++rg) {
            const f32x4 c = MFMA16(invu[rg].s, ldB(wsb, 0 + w, lane), Z4);
            const f32x4 b = MFMA16(invu[rg].s, ldB(wsb, 20 + w, lane), Z4);
            #pragma unroll
            for (int r = 0; r < 4; ++r) {
                const int rw = rg * 16 + gq * 4 + r;
                B1[rw * 72 + w * 16 + cl] = bf16rne(siluf(c[r]));
                B2[rw * 72 + w * 16 + cl] = bf16rne(siluf(b[r]));
            }
        }
    }
    __syncthreads();   // B1

    // ---- L2: B1 -> B3 (WC2), B2 -> B4 (WB2) ----
    {
        f32x4 c[2] = {Z4, Z4}, b[2] = {Z4, Z4};
        #pragma unroll
        for (int ks = 0; ks < 2; ++ks) {
            const s16x8 fc = ldB(wsb, 4 + w * 2 + ks, lane);
            const s16x8 fb = ldB(wsb, 24 + w * 2 + ks, lane);
            #pragma unroll
            for (int rg = 0; rg < 2; ++rg) {
                const s16x8 ac = ldA72(B1, rg * 16 + cl, ks, gq);
                const s16x8 ab = ldA72(B2, rg * 16 + cl, ks, gq);
                c[rg] = MFMA16(ac, fc, c[rg]);
                b[rg] = MFMA16(ab, fb, b[rg]);
            }
        }
        __syncthreads();   // B2a: done reading B1/B2
        #pragma unroll
        for (int rg = 0; rg < 2; ++rg)
            #pragma unroll
            for (int r = 0; r < 4; ++r) {
                const int rw = rg * 16 + gq * 4 + r;
                B3[rw * 72 + w * 16 + cl] = bf16rne(siluf(c[rg][r]));
                B4[rw * 72 + w * 16 + cl] = bf16rne(siluf(b[rg][r]));
            }
    }
    __syncthreads();   // B2

    // ---- L3: B3 -> B1 (WC3), B4 -> B2 (WB3) ----
    {
        f32x4 c[2] = {Z4, Z4}, b[2] = {Z4, Z4};
        #pragma unroll
        for (int ks = 0; ks < 2; ++ks) {
            const s16x8 fc = ldB(wsb, 12 + w * 2 + ks, lane);
            const s16x8 fb = ldB(wsb, 32 + w * 2 + ks, lane);
            #pragma unroll
            for (int rg = 0; rg < 2; ++rg) {
                const s16x8 ac = ldA72(B3, rg * 16 + cl, ks, gq);
                const s16x8 ab = ldA72(B4, rg * 16 + cl, ks, gq);
                c[rg] = MFMA16(ac, fc, c[rg]);
                b[rg] = MFMA16(ab, fb, b[rg]);
            }
        }
        __syncthreads();
        #pragma unroll
        for (int rg = 0; rg < 2; ++rg)
            #pragma unroll
            for (int r = 0; r < 4; ++r) {
                const int rw = rg * 16 + gq * 4 + r;
                B1[rw * 72 + w * 16 + cl] = bf16rne(siluf(c[rg][r]));
                B2[rw * 72 + w * 16 + cl] = bf16rne(siluf(b[rg][r]));
            }
    }
    __syncthreads();   // B3

    // ---- phase5a: h3 -> regs (both rgs), ob MFMAs ----
    s16x8 h3c[2][2], h3b[2][2];
    #pragma unroll
    for (int rg = 0; rg < 2; ++rg)
        #pragma unroll
        for (int ks = 0; ks < 2; ++ks) {
            h3c[rg][ks] = ldA72(B1, rg * 16 + cl, ks, gq);
            h3b[rg][ks] = ldA72(B2, rg * 16 + cl, ks, gq);
        }
    f32x4 obacc[2][2];
    #pragma unroll
    for (int tc = 0; tc < 2; ++tc) {
        const int T = w * 2 + tc;
        const s16x8 f0 = ldB(wsb, 104 + T * 2 + 0, lane);
        const s16x8 f1 = ldB(wsb, 104 + T * 2 + 1, lane);
        #pragma unroll
        for (int rg = 0; rg < 2; ++rg) {
            f32x4 c = MFMA16(h3b[rg][0], f0, Z4);
            obacc[rg][tc] = MFMA16(h3b[rg][1], f1, c);
        }
    }
    __syncthreads();   // B4a: B1/B2 free for P2

    // ---- phase5b (P2): out_s->B1, gate->B2, vy->B3 (bf16); v kept in regs ----
    unsigned int vpack[3][8];   // v bf16-packed: [comp][jp] for this thread's 16 channels
    {
        const int row = tid >> 3;
        const int c0  = (tid & 7) << 4;
        const size_t gn = (size_t)(n0 + row);
        const int e = eidx[row];
        const float y10 = y1f[row * 3], y11 = y1f[row * 3 + 1], y12 = y1f[row * 3 + 2];
        const float* sp  = Sin + gn * CC + c0;
        const float* vp  = Vin + (gn * CC + c0) * 3;
        const float* wsp = WSp + ((size_t)e * 5) * CC + c0;
        const float* wvp = WVp + ((size_t)e * 4) * CC + c0;
        unsigned int* B1d = (unsigned int*)B1;
        unsigned int* B2d = (unsigned int*)B2;
        unsigned int* B3d = (unsigned int*)B3;
        const int dbase = row * 68 + (c0 >> 1);
        #pragma unroll
        for (int jp = 0; jp < 8; ++jp) {
            const int c = 2 * jp;
            const float2 s2 = *(const float2*)(sp + c);
            const float2 va = *(const float2*)(vp + 3 * c);
            const float2 vb = *(const float2*)(vp + 3 * c + 2);
            const float2 vc = *(const float2*)(vp + 3 * c + 4);
            // channel c:   v = (va.x, va.y, vb.x) ; channel c+1: v = (vb.y, vc.x, vc.y)
            vpack[0][jp] = packbf(va.x, vb.y);
            vpack[1][jp] = packbf(va.y, vc.x);
            vpack[2][jp] = packbf(vb.x, vc.y);
            const float vv0 = va.x * va.x + va.y * va.y + vb.x * vb.x;
            const float vv1 = vb.y * vb.y + vc.x * vc.x + vc.y * vc.y;
            const float vy0 = va.x * y10 + va.y * y11 + vb.x * y12;
            const float vy1 = vb.y * y10 + vc.x * y11 + vc.y * y12;
            const float2 p0 = *(const float2*)(wsp + 0 * CC + c);
            const float2 p1 = *(const float2*)(wsp + 1 * CC + c);
            const float2 p2 = *(const float2*)(wsp + 2 * CC + c);
            const float2 p3 = *(const float2*)(wsp + 3 * CC + c);
            const float2 p4 = *(const float2*)(wsp + 4 * CC + c);
            const float2 q0 = *(const float2*)(wvp + 0 * CC + c);
            const float2 q1 = *(const float2*)(wvp + 1 * CC + c);
            const float2 q2 = *(const float2*)(wvp + 2 * CC + c);
            const float2 q3 = *(const float2*)(wvp + 3 * CC + c);
            const float s0 = s2.x, s1 = s2.y;
            const float ss0 = s0 * s0, ss1 = s1 * s1;
            const float os0 = p0.x * s0 + p1.x * ss0 + p2.x * vv0 + p3.x * (ss0 * s0) + p4.x * (s0 * vv0);
            const float os1 = p0.y * s1 + p1.y * ss1 + p2.y * vv1 + p3.y * (ss1 * s1) + p4.y * (s1 * vv1);
            const float gt0 = q0.x + q1.x * s0 + q2.x * ss0 + q3.x * vv0;
            const float gt1 = q0.y + q1.y * s1 + q2.y * ss1 + q3.y * vv1;
            B1d[dbase + jp] = packbf(os0, os1);
            B2d[dbase + jp] = packbf(gt0, gt1);
            B3d[dbase + jp] = packbf(vy0, vy1);
        }
    }
    __syncthreads();   // B4b

    // ---- m-phase: m1 -> B3 (in place over vy), m0 -> B4 ; prefetch SCp(msg0) ----
    float sc0[2][2][4];
    #pragma unroll
    for (int rg = 0; rg < 2; ++rg)
        #pragma unroll
        for (int tc = 0; tc < 2; ++tc)
            #pragma unroll
            for (int r = 0; r < 4; ++r) {
                const int rw = rg * 16 + gq * 4 + r;
                sc0[rg][tc][r] = SCp[(size_t)(n0 + rw) * 512 + (w * 2 + tc) * 16 + cl];
            }
    {
        f32x4 wc0[2][2], wc1[2][2];
        #pragma unroll
        for (int tc = 0; tc < 2; ++tc) {
            const int T = w * 2 + tc;
            const s16x8 a0 = ldB(wsb, 40 + (0 * 8 + T) * 2 + 0, lane);
            const s16x8 a1 = ldB(wsb, 40 + (0 * 8 + T) * 2 + 1, lane);
            const s16x8 b0 = ldB(wsb, 40 + (1 * 8 + T) * 2 + 0, lane);
            const s16x8 b1 = ldB(wsb, 40 + (1 * 8 + T) * 2 + 1, lane);
            #pragma unroll
            for (int rg = 0; rg < 2; ++rg) {
                f32x4 c = MFMA16(h3c[rg][0], a0, Z4);
                wc0[rg][tc] = MFMA16(h3c[rg][1], a1, c);
                f32x4 d = MFMA16(h3c[rg][0], b0, Z4);
                wc1[rg][tc] = MFMA16(h3c[rg][1], b1, d);
            }
        }
        #pragma unroll
        for (int rg = 0; rg < 2; ++rg)
            #pragma unroll
            for (int tc = 0; tc < 2; ++tc)
                #pragma unroll
                for (int r = 0; r < 4; ++r) {
                    const int rw = rg * 16 + gq * 4 + r;
                    const int col = (w * 2 + tc) * 16 + cl;
                    const float gt = bf2f(B2[rw * 136 + col]);
                    const float vy = bf2f(B3[rw * 136 + col]);
                    B3[rw * 136 + col] = bf16rne(INV_SQ6f * wc1[rg][tc][r] * gt * vy);
                    const float os = bf2f(B1[rw * 136 + col]);
                    const float m0 = INV_SQ2f * wc0[rg][tc][r] * os * y0f[rw] + etf[rw] * obacc[rg][tc][r];
                    B4[rw * 136 + col] = bf16rne(m0);
                }
    }
    __syncthreads();   // B5

    // ---- G1: msg0 = [m0|m1|os] @ [Wl0a;Wl0b;Wo0] + sc ----
    {
        f32x4 acc[2][2] = {{Z4, Z4}, {Z4, Z4}};
        #pragma unroll
        for (int ks = 0; ks < 12; ++ks) {
            const unsigned short* Xa = (ks < 4) ? B4 : (ks < 8) ? B3 : B1;
            s16x8 a[2];
            #pragma unroll
            for (int rg = 0; rg < 2; ++rg) a[rg] = ldA136(Xa, rg * 16 + cl, ks & 3, gq);
            #pragma unroll
            for (int tc = 0; tc < 2; ++tc) {
                const int T = w * 2 + tc;
                const int fi = (ks < 8) ? (120 + T * 8 + ks) : (184 + T * 4 + (ks - 8));
                const s16x8 bfrag = ldB(wsb, fi, lane);
                #pragma unroll
                for (int rg = 0; rg < 2; ++rg)
                    acc[rg][tc] = MFMA16(a[rg], bfrag, acc[rg][tc]);
            }
        }
        #pragma unroll
        for (int rg = 0; rg < 2; ++rg)
            #pragma unroll
            for (int tc = 0; tc < 2; ++tc)
                #pragma unroll
                for (int r = 0; r < 4; ++r) {
                    const int rw = rg * 16 + gq * 4 + r;
                    const size_t o = (size_t)(n0 + rw) * 512 + (w * 2 + tc) * 16 + cl;
                    OUT[o] = acc[rg][tc][r] + sc0[rg][tc][r];
                }
    }
    __syncthreads();   // B6

    // ---- phase8: a2 = INV_SQ2*w2*out_s (B1 in place); b = INV_SQ2*w3*gate*y0 -> B4 ----
    {
        f32x4 wc2[2][2], wc3[2][2];
        #pragma unroll
        for (int tc = 0; tc < 2; ++tc) {
            const int T = w * 2 + tc;
            const s16x8 a0 = ldB(wsb, 40 + (2 * 8 + T) * 2 + 0, lane);
            const s16x8 a1 = ldB(wsb, 40 + (2 * 8 + T) * 2 + 1, lane);
            const s16x8 b0 = ldB(wsb, 40 + (3 * 8 + T) * 2 + 0, lane);
            const s16x8 b1 = ldB(wsb, 40 + (3 * 8 + T) * 2 + 1, lane);
            #pragma unroll
            for (int rg = 0; rg < 2; ++rg) {
                f32x4 c = MFMA16(h3c[rg][0], a0, Z4);
                wc2[rg][tc] = MFMA16(h3c[rg][1], a1, c);
                f32x4 d = MFMA16(h3c[rg][0], b0, Z4);
                wc3[rg][tc] = MFMA16(h3c[rg][1], b1, d);
            }
        }
        #pragma unroll
        for (int rg = 0; rg < 2; ++rg)
            #pragma unroll
            for (int tc = 0; tc < 2; ++tc)
                #pragma unroll
                for (int r = 0; r < 4; ++r) {
                    const int rw = rg * 16 + gq * 4 + r;
                    const int col = (w * 2 + tc) * 16 + cl;
                    B1[rw * 136 + col] = bf16rne(INV_SQ2f * wc2[rg][tc][r] * bf2f(B1[rw * 136 + col]));
                    const float gt = bf2f(B2[rw * 136 + col]);
                    B4[rw * 136 + col] = bf16rne(INV_SQ2f * wc3[rg][tc][r] * gt * y0f[rw]);
                }
    }
    __syncthreads();   // B7

    // ---- G2: t = a2 @ Wl1[0:128] -> tacc ----
    f32x4 tacc[2][2] = {{Z4, Z4}, {Z4, Z4}};
    #pragma unroll
    for (int ks = 0; ks < 4; ++ks) {
        s16x8 a[2];
        #pragma unroll
        for (int rg = 0; rg < 2; ++rg) a[rg] = ldA136(B1, rg * 16 + cl, ks, gq);
        #pragma unroll
        for (int tc = 0; tc < 2; ++tc) {
            const int T = w * 2 + tc;
            const s16x8 bfrag = ldB(wsb, 216 + T * 8 + ks, lane);
            #pragma unroll
            for (int rg = 0; rg < 2; ++rg)
                tacc[rg][tc] = MFMA16(a[rg], bfrag, tacc[rg][tc]);
        }
    }
    __syncthreads();   // B8: B1 free for staging

    // ---- G3: 3 components; stage bv->B1, gv->B3 from regs (v) + LDS (b, gate) ----
    f32x4 acc3[3][2][2];
    #pragma unroll
    for (int i = 0; i < 3; ++i) {
        {   // stage component i (thread-linear)
            const int dbase = (tid >> 3) * 68 + (tid & 7) * 8;
            const unsigned int* bD = (const unsigned int*)B4;
            const unsigned int* gD = (const unsigned int*)B2;
            unsigned int* o1 = (unsigned int*)B1;
            unsigned int* o3 = (unsigned int*)B3;
            #pragma unroll
            for (int jp = 0; jp < 8; ++jp) {
                const unsigned int bd = bD[dbase + jp];
                const unsigned int gd = gD[dbase + jp];
                const float v0 = bf2f((unsigned short)(vpack[i][jp] & 0xffff));
                const float v1 = bf2f((unsigned short)(vpack[i][jp] >> 16));
                o1[dbase + jp] = packbf(bf2f((unsigned short)(bd & 0xffff)) * v0,
                                        bf2f((unsigned short)(bd >> 16)) * v1);
                o3[dbase + jp] = packbf(bf2f((unsigned short)(gd & 0xffff)) * v0,
                                        bf2f((unsigned short)(gd >> 16)) * v1);
            }
        }
        __syncthreads();
        #pragma unroll
        for (int rg = 0; rg < 2; ++rg)
            #pragma unroll
            for (int tc = 0; tc < 2; ++tc)
                acc3[i][rg][tc] = Z4;
        #pragma unroll
        for (int ks = 0; ks < 4; ++ks) {
            s16x8 a1[2], a3[2];
            #pragma unroll
            for (int rg = 0; rg < 2; ++rg) {
                a1[rg] = ldA136(B1, rg * 16 + cl, ks, gq);
                a3[rg] = ldA136(B3, rg * 16 + cl, ks, gq);
            }
            #pragma unroll
            for (int tc = 0; tc < 2; ++tc) {
                const int T = w * 2 + tc;
                const s16x8 fb = ldB(wsb, 216 + T * 8 + 4 + ks, lane);
                const s16x8 fg = ldB(wsb, 280 + T * 4 + ks, lane);
                #pragma unroll
                for (int rg = 0; rg < 2; ++rg) {
                    acc3[i][rg][tc] = MFMA16(a1[rg], fb, acc3[i][rg][tc]);
                    acc3[i][rg][tc] = MFMA16(a3[rg], fg, acc3[i][rg][tc]);
                }
            }
        }
        if (i < 2) __syncthreads();
    }

    // ---- epilogue: msg1 = G3 + t*y1_i + sc, contiguous 12B stores ----
    #pragma unroll
    for (int rg = 0; rg < 2; ++rg)
        #pragma unroll
        for (int tc = 0; tc < 2; ++tc)
            #pragma unroll
            for (int r = 0; r < 4; ++r) {
                const int rw = rg * 16 + gq * 4 + r;
                const int col = (w * 2 + tc) * 16 + cl;
                const size_t base = (size_t)(n0 + rw) * 512 + 128 + (size_t)col * 3;
                const float tv = tacc[rg][tc][r];
                #pragma unroll
                for (int i = 0; i < 3; ++i) {
                    const size_t o = base + i;
                    OUT[o] = acc3[i][rg][tc][r] + tv * y1f[rw * 3 + i] + SCp[o];
                }
            }
}

extern "C" void kernel_launch(void* const* d_in, const int* in_sizes, int n_in,
                              void* d_out, int out_size, void* d_ws, size_t ws_size,
                              hipStream_t stream)
{
    (void)in_sizes; (void)n_in; (void)out_size; (void)ws_size;
    const float* Sin  = (const float*)d_in[0];
    const float* Vin  = (const float*)d_in[1];
    const float* SCp  = (const float*)d_in[2];
    const float* ATT  = (const float*)d_in[3];
    const float* INVF = (const float*)d_in[4];
    const float* MNA  = (const float*)d_in[5];
    const float* MLEN = (const float*)d_in[6];
    const float* WSp  = (const float*)d_in[7];
    const float* WVp  = (const float*)d_in[8];
    const float* WC1  = (const float*)d_in[9];
    const float* WC2  = (const float*)d_in[10];
    const float* WC3  = (const float*)d_in[11];
    const float* WC4  = (const float*)d_in[12];
    const float* WB1  = (const float*)d_in[13];
    const float* WB2  = (const float*)d_in[14];
    const float* WB3  = (const float*)d_in[15];
    const float* WB4  = (const float*)d_in[16];
    const float* ESC  = (const float*)d_in[17];
    const float* WL0  = (const float*)d_in[18];
    const float* WL1  = (const float*)d_in[19];
    const float* WO0  = (const float*)d_in[20];
    const float* WO1  = (const float*)d_in[21];
    float* OUT = (float*)d_out;

    unsigned short* wsb = (unsigned short*)d_ws;
    hipLaunchKernelGGL(prep_frags, dim3(WS_FRAGS), dim3(64), 0, stream,
                       WC1, WC2, WC3, WB1, WB2, WB3, WC4, WB4,
                       WL0, WO0, WL1, WO1, wsb);
    // dynamic LDS: 4 buffers (8704 B) + smalls (768 B) = 35584 B -> 4 blocks/CU
    const size_t shbytes = (size_t)(4 * 8704 + 768);
    hipLaunchKernelGGL(epb_mfma, dim3(NNODES / BN), dim3(NT), shbytes, stream,
                       Sin, Vin, SCp, ATT, INVF, MNA, MLEN, WSp, WVp, ESC,
                       wsb, OUT);
}